// Round 10
// baseline (259.967 us; speedup 1.0000x reference)
//
#include <hip/hip_runtime.h>
#include <hip/hip_bf16.h>
#include <math.h>

#define HD 256
#define GB 128

typedef __attribute__((ext_vector_type(8))) short bf16x8;
typedef __attribute__((ext_vector_type(4))) float f32x4;
typedef __attribute__((ext_vector_type(2))) float f32x2;

__device__ __forceinline__ float bf2f(unsigned short u) {
  return __uint_as_float(((unsigned int)u) << 16);
}
__device__ __forceinline__ unsigned short f2bf(float f) {
  unsigned int u = __float_as_uint(f);
  unsigned int r = u + 0x7FFFu + ((u >> 16) & 1u);
  return (unsigned short)(r >> 16);
}

// ---------- fp8 e4m3 helpers ----------
__device__ __forceinline__ float f8dec(unsigned u) {
  unsigned s = (u >> 7) & 1u, e = (u >> 3) & 15u, m = u & 7u;
  float mag = e ? __uint_as_float(((e + 120u) << 23) | (m << 20))
                : (float)m * 0.001953125f;
  return s ? -mag : mag;
}
__device__ __forceinline__ unsigned f8enc(float x) {
#if __has_builtin(__builtin_amdgcn_cvt_pk_fp8_f32)
  return (unsigned)__builtin_amdgcn_cvt_pk_fp8_f32(x, x, 0, false) & 0xFFu;
#else
  float a = fabsf(x);
  unsigned s = x < 0.f ? 0x80u : 0u;
  if (a >= 440.f) return s | 0x7Eu;
  if (a < 0.015625f) {
    int q = (int)rintf(a * 512.f);
    return s | (unsigned)q;
  }
  unsigned u = __float_as_uint(a);
  u += 0x7FFFFu + ((u >> 20) & 1u);
  unsigned e = (u >> 23) - 120u;
  if (e >= 16u) return s | 0x7Eu;
  return s | (e << 3) | ((u >> 20) & 7u);
#endif
}

template<int FB>
__device__ __forceinline__ void load_row_f8(const unsigned char* p, float (&f)[FB]) {
  if constexpr (FB == 4) {
    unsigned u = *(const unsigned*)p;
#if __has_builtin(__builtin_amdgcn_cvt_pk_f32_fp8)
    f32x2 lo = __builtin_amdgcn_cvt_pk_f32_fp8((int)u, false);
    f32x2 hi = __builtin_amdgcn_cvt_pk_f32_fp8((int)u, true);
    f[0] = lo[0]; f[1] = lo[1]; f[2] = hi[0]; f[3] = hi[1];
#else
    f[0] = f8dec(u); f[1] = f8dec(u >> 8); f[2] = f8dec(u >> 16); f[3] = f8dec(u >> 24);
#endif
  } else {
    unsigned u = *(const unsigned short*)p;
#if __has_builtin(__builtin_amdgcn_cvt_pk_f32_fp8)
    f32x2 lo = __builtin_amdgcn_cvt_pk_f32_fp8((int)u, false);
    f[0] = lo[0]; f[1] = lo[1];
#else
    f[0] = f8dec(u); f[1] = f8dec(u >> 8);
#endif
  }
}

// ---------- merged prep: weight pack + x->fp8 + zero scores/deg/scan-state ----------
__global__ __launch_bounds__(256) void k_prep(const float* __restrict__ W0, const float* __restrict__ W1,
                                              const float* __restrict__ W2,
                                              unsigned short* __restrict__ Wt0,
                                              unsigned short* __restrict__ Wt1,
                                              unsigned short* __restrict__ Wt2,
                                              const float4* __restrict__ x1, const float4* __restrict__ x2,
                                              unsigned* __restrict__ x8, int n4,
                                              float* __restrict__ scores, int* __restrict__ deg, int nd,
                                              int* __restrict__ sstate, int ns) {
  int i = blockIdx.x * blockDim.x + threadIdx.x;
  if (i < 163840) {
    const float* W; unsigned short* Wt; int j;
    if (i < 32768)      { W = W0; Wt = Wt0; j = i; }
    else if (i < 98304) { W = W1; Wt = Wt1; j = i - 32768; }
    else                { W = W2; Wt = Wt2; j = i - 98304; }
    int k = j >> 8, c = j & 255;
    Wt[(((size_t)(k >> 3) * HD) + c) * 8 + (k & 7)] = f2bf(W[(size_t)k * HD + c]);
    return;
  }
  int j = i - 163840;
  if (j < 2 * n4) {
    float4 v = (j < n4) ? x1[j] : x2[j - n4];
    x8[j] = f8enc(v.x) | (f8enc(v.y) << 8) | (f8enc(v.z) << 16) | (f8enc(v.w) << 24);
    return;
  }
  j -= 2 * n4;
  if (j < GB * 512) { scores[j] = 0.f; return; }
  j -= GB * 512;
  if (j < nd) { deg[j] = 0; return; }
  j -= nd;
  if (j < ns) sstate[j] = 0;
}

__global__ void k_deg2(const int* __restrict__ dst1, const int* __restrict__ dst2,
                       int* __restrict__ deg, int e, int n0) {
  int i = blockIdx.x * blockDim.x + threadIdx.x;
  if (i >= 2 * e) return;
  int d = (i < e) ? dst1[i] : (dst2[i - e] + n0);
  atomicAdd(&deg[d], 1);
}

// ---------- single-pass decoupled-lookback scan ----------
// ticket, bflag[NB], bval[NB], bpre[NB]; all blocks co-resident (NB=157 << capacity)
__global__ __launch_bounds__(256) void k_scan1(const int* __restrict__ deg,
                                               int* __restrict__ row_ptr,
                                               float* __restrict__ dinv,
                                               int* __restrict__ cursor,
                                               int* __restrict__ ticket,
                                               int* __restrict__ bflag,
                                               int* __restrict__ bval,
                                               int* __restrict__ bpre,
                                               int n) {
  __shared__ int sh[256];
  __shared__ int s_bid, s_prev;
  int t = threadIdx.x;
  if (t == 0) s_bid = atomicAdd(ticket, 1);
  __syncthreads();
  int bid = s_bid;
  int i = bid * 256 + t;
  int v = (i < n) ? deg[i] : 0;
  sh[t] = v;
  __syncthreads();
  for (int off = 1; off < 256; off <<= 1) {
    int u = (t >= off) ? sh[t - off] : 0;
    __syncthreads();
    sh[t] += u;
    __syncthreads();
  }
  if (t == 0) {
    int total = sh[255];
    int excl = 0;
    if (bid > 0) {
      atomicExch(&bval[bid], total);
      __threadfence();
      atomicExch(&bflag[bid], 1);
      int pb = bid - 1;
      while (true) {
        int st;
        do { st = atomicAdd(&bflag[pb], 0); } while (st == 0);
        if (st == 2) { excl += atomicAdd(&bpre[pb], 0); break; }
        excl += atomicAdd(&bval[pb], 0);
        --pb;
      }
      atomicExch(&bpre[bid], excl + total);
      __threadfence();
      atomicExch(&bflag[bid], 2);
    } else {
      atomicExch(&bpre[0], total);
      __threadfence();
      atomicExch(&bflag[0], 2);
    }
    s_prev = excl;
  }
  __syncthreads();
  int prev = s_prev;
  if (i < n) {
    row_ptr[i] = prev + sh[t] - v;
    dinv[i] = rsqrtf((float)(v + 1));
    cursor[i] = 0;
    if (i == n - 1) row_ptr[n] = prev + sh[t];
  }
}

__global__ void k_build2(const int* __restrict__ ei1, const int* __restrict__ ei2,
                         const float* __restrict__ dinv, const int* __restrict__ row_ptr,
                         int* __restrict__ cursor, int2* __restrict__ csr, int e, int n0) {
  int i = blockIdx.x * blockDim.x + threadIdx.x;
  if (i >= 2 * e) return;
  int s, d;
  if (i < e) { s = ei1[i];          d = ei1[i + e]; }
  else       { s = ei2[i - e] + n0; d = ei2[i] + n0; }
  int pos = atomicAdd(&cursor[d], 1);
  int idx = row_ptr[d] + pos;
  csr[idx] = make_int2(s, __float_as_int(dinv[s] * dinv[d]));
}

// ---------- MFMA bf16 GEMM: 32 rows/wave, C[M,256] = A[M,K] @ W ----------
template<bool BR, bool F8OUT>
__global__ __launch_bounds__(256) void k_gemm_bf(const unsigned short* __restrict__ A,
                                                 const unsigned short* __restrict__ Wt,
                                                 const float* __restrict__ bias,
                                                 void* __restrict__ Cv,
                                                 int K, int M) {
  const int w = threadIdx.x >> 6;
  const int lane = threadIdx.x & 63;
  const int bm = blockIdx.x * 128 + w * 32;
  const int bn = blockIdx.y * 128;
  const int rr = lane & 15;
  const int kg0 = lane >> 4;
  const int r0c = min(bm + rr, M - 1);
  const int r1c = min(bm + 16 + rr, M - 1);
  f32x4 acc[2][8];
#pragma unroll
  for (int h = 0; h < 2; ++h)
#pragma unroll
    for (int i = 0; i < 8; ++i) acc[h][i] = (f32x4){0.f, 0.f, 0.f, 0.f};

  const unsigned short* a0 = A + (size_t)r0c * K + kg0 * 8;
  const unsigned short* a1 = A + (size_t)r1c * K + kg0 * 8;
  for (int k0 = 0; k0 < K; k0 += 32) {
    bf16x8 av0 = *(const bf16x8*)(a0 + k0);
    bf16x8 av1 = *(const bf16x8*)(a1 + k0);
    const unsigned short* bbase =
        Wt + (((size_t)((k0 >> 3) + kg0) * HD) + bn + rr) * 8;
#pragma unroll
    for (int nt = 0; nt < 8; ++nt) {
      bf16x8 b = *(const bf16x8*)(bbase + (size_t)nt * 16 * 8);
      acc[0][nt] = __builtin_amdgcn_mfma_f32_16x16x32_bf16(av0, b, acc[0][nt], 0, 0, 0);
      acc[1][nt] = __builtin_amdgcn_mfma_f32_16x16x32_bf16(av1, b, acc[1][nt], 0, 0, 0);
    }
  }
  const int crow = bm + (lane >> 4) * 4;
  const int ccol = bn + rr;
#pragma unroll
  for (int h = 0; h < 2; ++h) {
#pragma unroll
    for (int nt = 0; nt < 8; ++nt) {
      float bb = BR ? bias[ccol + nt * 16] : 0.f;
#pragma unroll
      for (int r = 0; r < 4; ++r) {
        int row = crow + h * 16 + r;
        if (row < M) {
          float v = acc[h][nt][r];
          if (BR) v = fmaxf(v + bb, 0.f);
          size_t idx = (size_t)row * HD + ccol + nt * 16;
          if constexpr (F8OUT) ((unsigned char*)Cv)[idx] = (unsigned char)f8enc(v);
          else                 ((unsigned short*)Cv)[idx] = f2bf(v);
        }
      }
    }
  }
}

// ---------- fused gather: fp8 in, bf16 out; 8-edge unroll ----------
template<int FB, bool BR>
__global__ __launch_bounds__(256) void k_gathf8(const unsigned char* __restrict__ y,
                                                const int* __restrict__ row_ptr,
                                                const int2* __restrict__ csr,
                                                const float* __restrict__ dinv,
                                                const float* __restrict__ bias,
                                                unsigned short* __restrict__ out, int n) {
  constexpr int F = FB * 64;
  int node = (blockIdx.x * blockDim.x + threadIdx.x) >> 6;
  int lane = threadIdx.x & 63;
  if (node >= n) return;
  float di = dinv[node];
  float c = di * di;
  float self[FB], acc0[FB], acc1[FB];
  load_row_f8<FB>(y + (size_t)node * F + lane * FB, self);
#pragma unroll
  for (int q = 0; q < FB; ++q) { acc0[q] = c * self[q]; acc1[q] = 0.f; }

  int e = row_ptr[node], end = row_ptr[node + 1];
  while (e < end) {
    int cnt = min(end - e, 64);
    int2 ew = make_int2(0, 0);
    if (lane < cnt) ew = csr[e + lane];
    int j = 0;
    for (; j + 8 <= cnt; j += 8) {
      int s[8]; float wt[8];
#pragma unroll
      for (int q = 0; q < 8; ++q) {
        s[q] = __shfl(ew.x, j + q);
        wt[q] = __int_as_float(__shfl(ew.y, j + q));
      }
      float r[8][FB];
#pragma unroll
      for (int q = 0; q < 8; ++q)
        load_row_f8<FB>(y + (size_t)s[q] * F + lane * FB, r[q]);
#pragma unroll
      for (int q = 0; q < 8; q += 2) {
#pragma unroll
        for (int d = 0; d < FB; ++d) {
          acc0[d] = fmaf(wt[q], r[q][d], acc0[d]);
          acc1[d] = fmaf(wt[q + 1], r[q + 1][d], acc1[d]);
        }
      }
    }
    for (; j < cnt; ++j) {
      int s0 = __shfl(ew.x, j);
      float w0 = __int_as_float(__shfl(ew.y, j));
      float r0[FB];
      load_row_f8<FB>(y + (size_t)s0 * F + lane * FB, r0);
#pragma unroll
      for (int q = 0; q < FB; ++q) acc0[q] = fmaf(w0, r0[q], acc0[q]);
    }
    e += cnt;
  }
  unsigned short o[FB];
#pragma unroll
  for (int q = 0; q < FB; ++q) {
    float v = acc0[q] + acc1[q];
    if (BR) v = fmaxf(v + bias[lane * FB + q], 0.f);
    o[q] = f2bf(v);
  }
  if constexpr (FB == 4) {
    ushort4 ov; ov.x = o[0]; ov.y = o[1]; ov.z = o[2]; ov.w = o[3];
    *(ushort4*)(out + (size_t)node * F + lane * FB) = ov;
  } else {
    ushort2 ov; ov.x = o[0]; ov.y = o[1];
    *(ushort2*)(out + (size_t)node * F + lane * FB) = ov;
  }
}

// ---------- pool over merged node space (bf16 in) ----------
__global__ __launch_bounds__(256) void k_pool4(const unsigned short* __restrict__ h,
                                               const int* __restrict__ batch1,
                                               const int* __restrict__ batch2,
                                               float* __restrict__ scores,
                                               int n, int n0) {
  int wave = (blockIdx.x * blockDim.x + threadIdx.x) >> 6;
  int lane = threadIdx.x & 63;
  int beg = wave * 32;
  if (beg >= n) return;
  int end = min(beg + 32, n);
  bool g1 = beg >= n0;
  const int* bat = g1 ? batch2 : batch1;
  int boff = g1 ? n0 : 0;
  int coff = g1 ? HD : 0;
  float ax = 0.f, ay = 0.f, az = 0.f, aw = 0.f;
  int cur = bat[beg - boff];
  for (int i = beg; i < end; ++i) {
    int b = bat[i - boff];
    if (b != cur) {
      float* srow = &scores[(size_t)cur * 512 + coff + lane * 4];
      atomicAdd(&srow[0], ax); atomicAdd(&srow[1], ay);
      atomicAdd(&srow[2], az); atomicAdd(&srow[3], aw);
      ax = ay = az = aw = 0.f;
      cur = b;
    }
    ushort4 v = reinterpret_cast<const ushort4*>(h + (size_t)i * HD)[lane];
    ax += bf2f(v.x); ay += bf2f(v.y); az += bf2f(v.z); aw += bf2f(v.w);
  }
  float* srow = &scores[(size_t)cur * 512 + coff + lane * 4];
  atomicAdd(&srow[0], ax); atomicAdd(&srow[1], ay);
  atomicAdd(&srow[2], az); atomicAdd(&srow[3], aw);
}

// ---------- head layer 0 ----------
__global__ __launch_bounds__(256) void k_head_a(const float* __restrict__ scores,
                                                const float* __restrict__ lw0,
                                                const float* __restrict__ lb0,
                                                float* __restrict__ h1) {
  __shared__ float s_in[512];
  __shared__ float part[4][64];
  const int r = blockIdx.x, ct = blockIdx.y;
  const int t = threadIdx.x;
  s_in[t]       = scores[(size_t)r * 512 + t];
  s_in[t + 256] = scores[(size_t)r * 512 + t + 256];
  __syncthreads();
  const int l = t & 63, w = t >> 6;
  const int col = ct * 64 + l;
  float acc = 0.f;
  const float* wp = lw0 + (size_t)(w * 128) * 256 + col;
  const float* sp = s_in + w * 128;
#pragma unroll 8
  for (int k = 0; k < 128; ++k) acc = fmaf(sp[k], wp[(size_t)k * 256], acc);
  part[w][l] = acc;
  __syncthreads();
  if (t < 64) {
    float v = part[0][t] + part[1][t] + part[2][t] + part[3][t] + lb0[ct * 64 + t];
    h1[(size_t)r * 256 + ct * 64 + t] = fmaxf(v, 0.f);
  }
}

// ---------- head layers 1+2 ----------
__global__ __launch_bounds__(256) void k_head_b(const float* __restrict__ h1,
                                                const float* __restrict__ lw1,
                                                const float* __restrict__ lb1,
                                                const float* __restrict__ lw2,
                                                const float* __restrict__ lb2,
                                                float* __restrict__ out) {
  __shared__ float s_in[256];
  __shared__ float part[2][128];
  __shared__ float s_h2[128];
  __shared__ float red[4];
  const int r = blockIdx.x;
  const int t = threadIdx.x;
  s_in[t] = h1[(size_t)r * 256 + t];
  __syncthreads();
  const int l = t & 127, w = t >> 7;
  float acc = 0.f;
  const float* wp = lw1 + (size_t)(w * 128) * 128 + l;
  const float* sp = s_in + w * 128;
#pragma unroll 8
  for (int k = 0; k < 128; ++k) acc = fmaf(sp[k], wp[(size_t)k * 128], acc);
  part[w][l] = acc;
  __syncthreads();
  if (t < 128) s_h2[t] = fmaxf(part[0][t] + part[1][t] + lb1[t], 0.f);
  __syncthreads();
  float p = (t < 128) ? s_h2[t] * lw2[t] : 0.f;
#pragma unroll
  for (int off = 32; off; off >>= 1) p += __shfl_down(p, off);
  if ((t & 63) == 0) red[t >> 6] = p;
  __syncthreads();
  if (t == 0) {
    float z = red[0] + red[1] + red[2] + red[3] + lb2[0];
    out[r] = 1.f / (1.f + expf(-z));
  }
}

extern "C" void kernel_launch(void* const* d_in, const int* in_sizes, int n_in,
                              void* d_out, int out_size, void* d_ws, size_t ws_size,
                              hipStream_t stream) {
  const float* x1 = (const float*)d_in[0];
  const float* x2 = (const float*)d_in[1];
  const int* ei1 = (const int*)d_in[2];
  const int* ei2 = (const int*)d_in[3];
  const int* batch1 = (const int*)d_in[4];
  const int* batch2 = (const int*)d_in[5];
  const float* W0 = (const float*)d_in[6];  const float* b0 = (const float*)d_in[7];
  const float* W1 = (const float*)d_in[8];  const float* b1 = (const float*)d_in[9];
  const float* W2 = (const float*)d_in[10]; const float* b2 = (const float*)d_in[11];
  const float* lw0 = (const float*)d_in[12]; const float* lb0 = (const float*)d_in[13];
  const float* lw1 = (const float*)d_in[14]; const float* lb1 = (const float*)d_in[15];
  const float* lw2 = (const float*)d_in[16]; const float* lb2 = (const float*)d_in[17];
  float* out = (float*)d_out;

  const int N = in_sizes[0] / 128;   // 20000
  const int E = in_sizes[2] / 2;     // 320000
  const int N2 = 2 * N, E2 = 2 * E;
  const int NB = (N2 + 255) / 256;   // 157

  char* p = (char*)d_ws;
  unsigned char*  x8   = (unsigned char*)p;  p += (size_t)N2 * 128;
  unsigned short* aggx = (unsigned short*)p; p += (size_t)N2 * 128 * 2;
  unsigned short* h    = (unsigned short*)p; p += (size_t)N2 * HD * 2;
  unsigned char*  y    = (unsigned char*)p;  p += (size_t)N2 * HD;
  unsigned short* Wt0  = (unsigned short*)p; p += (size_t)128 * HD * 2;
  unsigned short* Wt1  = (unsigned short*)p; p += (size_t)HD * HD * 2;
  unsigned short* Wt2  = (unsigned short*)p; p += (size_t)HD * HD * 2;
  float* dinv   = (float*)p; p += (size_t)N2 * 4;
  float* scores = (float*)p; p += (size_t)GB * 512 * 4;
  float* h1     = (float*)p; p += (size_t)GB * 256 * 4;
  int2* csr    = (int2*)p; p += (size_t)E2 * 8;
  int* deg     = (int*)p; p += (size_t)N2 * 4;
  int* row_ptr = (int*)p; p += (size_t)(N2 + 1) * 4;
  int* cursor  = (int*)p; p += (size_t)N2 * 4;
  int* ticket  = (int*)p; p += 4;            // zeroed by prep (sstate region start)
  int* bflag   = (int*)p; p += (size_t)NB * 4;
  int* bval    = (int*)p; p += (size_t)NB * 4;
  int* bpre    = (int*)p; p += (size_t)NB * 4;

  // prep: weights pack + x->fp8 + zero scores/deg + zero ticket+bflag (NB+1 ints)
  int n4 = N * 128 / 4;
  int ns = 1 + NB;                           // ticket + bflag (contiguous)
  int prep_total = 163840 + 2 * n4 + GB * 512 + N2 + ns;
  k_prep<<<(prep_total + 255) / 256, 256, 0, stream>>>(
      W0, W1, W2, Wt0, Wt1, Wt2,
      (const float4*)x1, (const float4*)x2, (unsigned*)x8, n4, scores, deg, N2,
      ticket, ns);

  // merged CSR
  k_deg2<<<(2 * E + 255) / 256, 256, 0, stream>>>(ei1 + E, ei2 + E, deg, E, N);
  k_scan1<<<NB, 256, 0, stream>>>(deg, row_ptr, dinv, cursor, ticket, bflag, bval, bpre, N2);
  k_build2<<<(2 * E + 255) / 256, 256, 0, stream>>>(ei1, ei2, dinv, row_ptr,
                                                    cursor, csr, E, N);

  dim3 ggrid((N2 + 127) / 128, 2);
  // layer 0: aggregate fp8 x (128-dim), then bf16 GEMM with bias+relu -> h (bf16)
  k_gathf8<2, false><<<(N2 + 3) / 4, 256, 0, stream>>>(x8, row_ptr, csr, dinv,
                                                       nullptr, aggx, N2);
  k_gemm_bf<true, false><<<ggrid, 256, 0, stream>>>(aggx, Wt0, b0, h, 128, N2);
  // layer 1
  k_gemm_bf<false, true><<<ggrid, 256, 0, stream>>>(h, Wt1, nullptr, y, HD, N2);
  k_gathf8<4, true><<<(N2 + 3) / 4, 256, 0, stream>>>(y, row_ptr, csr, dinv,
                                                      b1, h, N2);
  // layer 2
  k_gemm_bf<false, true><<<ggrid, 256, 0, stream>>>(h, Wt2, nullptr, y, HD, N2);
  k_gathf8<4, true><<<(N2 + 3) / 4, 256, 0, stream>>>(y, row_ptr, csr, dinv,
                                                      b2, h, N2);

  int waves = N2 / 32;
  k_pool4<<<(waves + 3) / 4, 256, 0, stream>>>(h, batch1, batch2, scores, N2, N);

  dim3 hgrid(GB, 4);
  k_head_a<<<hgrid, 256, 0, stream>>>(scores, lw0, lb0, h1);
  k_head_b<<<GB, 256, 0, stream>>>(h1, lw1, lb1, lw2, lb2, out);
}

// Round 11
// 239.409 us; speedup vs baseline: 1.0859x; 1.0859x over previous
//
#include <hip/hip_runtime.h>
#include <hip/hip_bf16.h>
#include <math.h>

#define HD 256
#define GB 128

typedef __attribute__((ext_vector_type(8))) short bf16x8;
typedef __attribute__((ext_vector_type(4))) float f32x4;
typedef __attribute__((ext_vector_type(2))) float f32x2;

__device__ __forceinline__ float bf2f(unsigned short u) {
  return __uint_as_float(((unsigned int)u) << 16);
}
__device__ __forceinline__ unsigned short f2bf(float f) {
  unsigned int u = __float_as_uint(f);
  unsigned int r = u + 0x7FFFu + ((u >> 16) & 1u);
  return (unsigned short)(r >> 16);
}

// ---------- fp8 e4m3 helpers ----------
__device__ __forceinline__ float f8dec(unsigned u) {
  unsigned s = (u >> 7) & 1u, e = (u >> 3) & 15u, m = u & 7u;
  float mag = e ? __uint_as_float(((e + 120u) << 23) | (m << 20))
                : (float)m * 0.001953125f;
  return s ? -mag : mag;
}
__device__ __forceinline__ unsigned f8enc(float x) {
#if __has_builtin(__builtin_amdgcn_cvt_pk_fp8_f32)
  return (unsigned)__builtin_amdgcn_cvt_pk_fp8_f32(x, x, 0, false) & 0xFFu;
#else
  float a = fabsf(x);
  unsigned s = x < 0.f ? 0x80u : 0u;
  if (a >= 440.f) return s | 0x7Eu;
  if (a < 0.015625f) {
    int q = (int)rintf(a * 512.f);
    return s | (unsigned)q;
  }
  unsigned u = __float_as_uint(a);
  u += 0x7FFFFu + ((u >> 20) & 1u);
  unsigned e = (u >> 23) - 120u;
  if (e >= 16u) return s | 0x7Eu;
  return s | (e << 3) | ((u >> 20) & 7u);
#endif
}

template<int FB>
__device__ __forceinline__ void load_row_f8(const unsigned char* p, float (&f)[FB]) {
  if constexpr (FB == 4) {
    unsigned u = *(const unsigned*)p;
#if __has_builtin(__builtin_amdgcn_cvt_pk_f32_fp8)
    f32x2 lo = __builtin_amdgcn_cvt_pk_f32_fp8((int)u, false);
    f32x2 hi = __builtin_amdgcn_cvt_pk_f32_fp8((int)u, true);
    f[0] = lo[0]; f[1] = lo[1]; f[2] = hi[0]; f[3] = hi[1];
#else
    f[0] = f8dec(u); f[1] = f8dec(u >> 8); f[2] = f8dec(u >> 16); f[3] = f8dec(u >> 24);
#endif
  } else {
    unsigned u = *(const unsigned short*)p;
#if __has_builtin(__builtin_amdgcn_cvt_pk_f32_fp8)
    f32x2 lo = __builtin_amdgcn_cvt_pk_f32_fp8((int)u, false);
    f[0] = lo[0]; f[1] = lo[1];
#else
    f[0] = f8dec(u); f[1] = f8dec(u >> 8);
#endif
  }
}

// ---------- merged prep: weight pack (bf16) + x->fp8 + zero scores/deg ----------
__global__ __launch_bounds__(256) void k_prep(const float* __restrict__ W0, const float* __restrict__ W1,
                                              const float* __restrict__ W2,
                                              unsigned short* __restrict__ Wt0,
                                              unsigned short* __restrict__ Wt1,
                                              unsigned short* __restrict__ Wt2,
                                              const float4* __restrict__ x1, const float4* __restrict__ x2,
                                              unsigned* __restrict__ x8, int n4,
                                              float* __restrict__ scores, int* __restrict__ deg, int nd) {
  int i = blockIdx.x * blockDim.x + threadIdx.x;
  if (i < 163840) {
    const float* W; unsigned short* Wt; int j;
    if (i < 32768)      { W = W0; Wt = Wt0; j = i; }
    else if (i < 98304) { W = W1; Wt = Wt1; j = i - 32768; }
    else                { W = W2; Wt = Wt2; j = i - 98304; }
    int k = j >> 8, c = j & 255;
    Wt[(((size_t)(k >> 3) * HD) + c) * 8 + (k & 7)] = f2bf(W[(size_t)k * HD + c]);
    return;
  }
  int j = i - 163840;
  if (j < 2 * n4) {
    float4 v = (j < n4) ? x1[j] : x2[j - n4];
    x8[j] = f8enc(v.x) | (f8enc(v.y) << 8) | (f8enc(v.z) << 16) | (f8enc(v.w) << 24);
    return;
  }
  j -= 2 * n4;
  if (j < GB * 512) { scores[j] = 0.f; return; }
  j -= GB * 512;
  if (j < nd) deg[j] = 0;
}

__global__ void k_deg2(const int* __restrict__ dst1, const int* __restrict__ dst2,
                       int* __restrict__ deg, int e, int n0) {
  int i = blockIdx.x * blockDim.x + threadIdx.x;
  if (i >= 2 * e) return;
  int d = (i < e) ? dst1[i] : (dst2[i - e] + n0);
  atomicAdd(&deg[d], 1);
}

// ---------- 3-phase scan ----------
__global__ __launch_bounds__(256) void k_scan_a(const int* __restrict__ deg,
                                                int* __restrict__ partial, int n) {
  __shared__ int sh[256];
  int i = blockIdx.x * 256 + threadIdx.x;
  int v = (i < n) ? deg[i] : 0;
  sh[threadIdx.x] = v;
  __syncthreads();
#pragma unroll
  for (int off = 128; off; off >>= 1) {
    if (threadIdx.x < off) sh[threadIdx.x] += sh[threadIdx.x + off];
    __syncthreads();
  }
  if (threadIdx.x == 0) partial[blockIdx.x] = sh[0];
}

__global__ __launch_bounds__(256) void k_scan_b(int* __restrict__ partial, int nb,
                                                int* __restrict__ row_ptr, int n, int e_total) {
  __shared__ int sh[256];
  int t = threadIdx.x;
  int v = (t < nb) ? partial[t] : 0;
  sh[t] = v;
  __syncthreads();
#pragma unroll
  for (int off = 1; off < 256; off <<= 1) {
    int u = (t >= off) ? sh[t - off] : 0;
    __syncthreads();
    sh[t] += u;
    __syncthreads();
  }
  if (t < nb) partial[t] = sh[t] - v;
  if (t == 0) row_ptr[n] = e_total;
}

__global__ __launch_bounds__(256) void k_scan_c(const int* __restrict__ deg,
                                                const int* __restrict__ partial,
                                                int* __restrict__ row_ptr,
                                                float* __restrict__ dinv,
                                                int* __restrict__ cursor, int n) {
  __shared__ int sh[256];
  int i = blockIdx.x * 256 + threadIdx.x;
  int t = threadIdx.x;
  int v = (i < n) ? deg[i] : 0;
  sh[t] = v;
  __syncthreads();
#pragma unroll
  for (int off = 1; off < 256; off <<= 1) {
    int u = (t >= off) ? sh[t - off] : 0;
    __syncthreads();
    sh[t] += u;
    __syncthreads();
  }
  if (i < n) {
    row_ptr[i] = sh[t] - v + partial[blockIdx.x];
    dinv[i] = rsqrtf((float)(v + 1));
    cursor[i] = 0;
  }
}

__global__ void k_build2(const int* __restrict__ ei1, const int* __restrict__ ei2,
                         const float* __restrict__ dinv, const int* __restrict__ row_ptr,
                         int* __restrict__ cursor, int2* __restrict__ csr, int e, int n0) {
  int i = blockIdx.x * blockDim.x + threadIdx.x;
  if (i >= 2 * e) return;
  int s, d;
  if (i < e) { s = ei1[i];          d = ei1[i + e]; }
  else       { s = ei2[i - e] + n0; d = ei2[i] + n0; }
  int pos = atomicAdd(&cursor[d], 1);
  int idx = row_ptr[d] + pos;
  csr[idx] = make_int2(s, __float_as_int(dinv[s] * dinv[d]));
}

// ---------- MFMA bf16 GEMM: C[M,256] = A[M,K] @ W; out bf16(+bias+relu) or fp8 ----------
template<bool BR, bool F8OUT>
__global__ __launch_bounds__(256) void k_gemm_bf(const unsigned short* __restrict__ A,
                                                 const unsigned short* __restrict__ Wt,
                                                 const float* __restrict__ bias,
                                                 void* __restrict__ Cv,
                                                 int K) {
  const int w = threadIdx.x >> 6;
  const int lane = threadIdx.x & 63;
  const int bm = blockIdx.x * 64 + w * 16;
  const int bn = blockIdx.y * 128;
  const int row = bm + (lane & 15);
  const int kg0 = lane >> 4;
  f32x4 acc[8];
#pragma unroll
  for (int i = 0; i < 8; ++i) acc[i] = (f32x4){0.f, 0.f, 0.f, 0.f};

  const unsigned short* arow = A + (size_t)row * K + kg0 * 8;
  for (int k0 = 0; k0 < K; k0 += 32) {
    bf16x8 a = *(const bf16x8*)(arow + k0);
    const unsigned short* bbase =
        Wt + (((size_t)((k0 >> 3) + kg0) * HD) + bn + (lane & 15)) * 8;
#pragma unroll
    for (int nt = 0; nt < 8; ++nt) {
      bf16x8 b = *(const bf16x8*)(bbase + (size_t)nt * 16 * 8);
      acc[nt] = __builtin_amdgcn_mfma_f32_16x16x32_bf16(a, b, acc[nt], 0, 0, 0);
    }
  }
  const int crow = bm + (lane >> 4) * 4;
  const int ccol = bn + (lane & 15);
#pragma unroll
  for (int nt = 0; nt < 8; ++nt) {
    float bb = BR ? bias[ccol + nt * 16] : 0.f;
#pragma unroll
    for (int r = 0; r < 4; ++r) {
      float v = acc[nt][r];
      if (BR) v = fmaxf(v + bb, 0.f);
      size_t idx = (size_t)(crow + r) * HD + ccol + nt * 16;
      if constexpr (F8OUT) ((unsigned char*)Cv)[idx] = (unsigned char)f8enc(v);
      else                 ((unsigned short*)Cv)[idx] = f2bf(v);
    }
  }
}

// ---------- fused gather: fp8 in, bf16 out; FB fp8 elems/lane (F = FB*64 feats) ----------
template<int FB, bool BR>
__global__ __launch_bounds__(256) void k_gathf8(const unsigned char* __restrict__ y,
                                                const int* __restrict__ row_ptr,
                                                const int2* __restrict__ csr,
                                                const float* __restrict__ dinv,
                                                const float* __restrict__ bias,
                                                unsigned short* __restrict__ out, int n) {
  constexpr int F = FB * 64;
  int node = (blockIdx.x * blockDim.x + threadIdx.x) >> 6;
  int lane = threadIdx.x & 63;
  if (node >= n) return;
  float di = dinv[node];
  float c = di * di;
  float self[FB], acc0[FB], acc1[FB];
  load_row_f8<FB>(y + (size_t)node * F + lane * FB, self);
#pragma unroll
  for (int q = 0; q < FB; ++q) { acc0[q] = c * self[q]; acc1[q] = 0.f; }

  int e = row_ptr[node], end = row_ptr[node + 1];
  while (e < end) {
    int cnt = min(end - e, 64);
    int2 ew = make_int2(0, 0);
    if (lane < cnt) ew = csr[e + lane];
    int j = 0;
    for (; j + 4 <= cnt; j += 4) {
      int s0 = __shfl(ew.x, j + 0), s1 = __shfl(ew.x, j + 1);
      int s2 = __shfl(ew.x, j + 2), s3 = __shfl(ew.x, j + 3);
      float w0 = __int_as_float(__shfl(ew.y, j + 0));
      float w1 = __int_as_float(__shfl(ew.y, j + 1));
      float w2 = __int_as_float(__shfl(ew.y, j + 2));
      float w3 = __int_as_float(__shfl(ew.y, j + 3));
      float r0[FB], r1[FB], r2[FB], r3[FB];
      load_row_f8<FB>(y + (size_t)s0 * F + lane * FB, r0);
      load_row_f8<FB>(y + (size_t)s1 * F + lane * FB, r1);
      load_row_f8<FB>(y + (size_t)s2 * F + lane * FB, r2);
      load_row_f8<FB>(y + (size_t)s3 * F + lane * FB, r3);
#pragma unroll
      for (int q = 0; q < FB; ++q) {
        acc0[q] = fmaf(w0, r0[q], acc0[q]);
        acc1[q] = fmaf(w1, r1[q], acc1[q]);
        acc0[q] = fmaf(w2, r2[q], acc0[q]);
        acc1[q] = fmaf(w3, r3[q], acc1[q]);
      }
    }
    for (; j < cnt; ++j) {
      int s0 = __shfl(ew.x, j);
      float w0 = __int_as_float(__shfl(ew.y, j));
      float r0[FB];
      load_row_f8<FB>(y + (size_t)s0 * F + lane * FB, r0);
#pragma unroll
      for (int q = 0; q < FB; ++q) acc0[q] = fmaf(w0, r0[q], acc0[q]);
    }
    e += cnt;
  }
  unsigned short o[FB];
#pragma unroll
  for (int q = 0; q < FB; ++q) {
    float v = acc0[q] + acc1[q];
    if (BR) v = fmaxf(v + bias[lane * FB + q], 0.f);
    o[q] = f2bf(v);
  }
  if constexpr (FB == 4) {
    ushort4 ov; ov.x = o[0]; ov.y = o[1]; ov.z = o[2]; ov.w = o[3];
    *(ushort4*)(out + (size_t)node * F + lane * FB) = ov;
  } else {
    ushort2 ov; ov.x = o[0]; ov.y = o[1];
    *(ushort2*)(out + (size_t)node * F + lane * FB) = ov;
  }
}

// ---------- pool over merged node space (bf16 in) ----------
__global__ __launch_bounds__(256) void k_pool4(const unsigned short* __restrict__ h,
                                               const int* __restrict__ batch1,
                                               const int* __restrict__ batch2,
                                               float* __restrict__ scores,
                                               int n, int n0) {
  int wave = (blockIdx.x * blockDim.x + threadIdx.x) >> 6;
  int lane = threadIdx.x & 63;
  int beg = wave * 32;
  if (beg >= n) return;
  int end = min(beg + 32, n);
  bool g1 = beg >= n0;
  const int* bat = g1 ? batch2 : batch1;
  int boff = g1 ? n0 : 0;
  int coff = g1 ? HD : 0;
  float ax = 0.f, ay = 0.f, az = 0.f, aw = 0.f;
  int cur = bat[beg - boff];
  for (int i = beg; i < end; ++i) {
    int b = bat[i - boff];
    if (b != cur) {
      float* srow = &scores[(size_t)cur * 512 + coff + lane * 4];
      atomicAdd(&srow[0], ax); atomicAdd(&srow[1], ay);
      atomicAdd(&srow[2], az); atomicAdd(&srow[3], aw);
      ax = ay = az = aw = 0.f;
      cur = b;
    }
    ushort4 v = reinterpret_cast<const ushort4*>(h + (size_t)i * HD)[lane];
    ax += bf2f(v.x); ay += bf2f(v.y); az += bf2f(v.z); aw += bf2f(v.w);
  }
  float* srow = &scores[(size_t)cur * 512 + coff + lane * 4];
  atomicAdd(&srow[0], ax); atomicAdd(&srow[1], ay);
  atomicAdd(&srow[2], az); atomicAdd(&srow[3], aw);
}

// ---------- head layer 0 ----------
__global__ __launch_bounds__(256) void k_head_a(const float* __restrict__ scores,
                                                const float* __restrict__ lw0,
                                                const float* __restrict__ lb0,
                                                float* __restrict__ h1) {
  __shared__ float s_in[512];
  __shared__ float part[4][64];
  const int r = blockIdx.x, ct = blockIdx.y;
  const int t = threadIdx.x;
  s_in[t]       = scores[(size_t)r * 512 + t];
  s_in[t + 256] = scores[(size_t)r * 512 + t + 256];
  __syncthreads();
  const int l = t & 63, w = t >> 6;
  const int col = ct * 64 + l;
  float acc = 0.f;
  const float* wp = lw0 + (size_t)(w * 128) * 256 + col;
  const float* sp = s_in + w * 128;
#pragma unroll 8
  for (int k = 0; k < 128; ++k) acc = fmaf(sp[k], wp[(size_t)k * 256], acc);
  part[w][l] = acc;
  __syncthreads();
  if (t < 64) {
    float v = part[0][t] + part[1][t] + part[2][t] + part[3][t] + lb0[ct * 64 + t];
    h1[(size_t)r * 256 + ct * 64 + t] = fmaxf(v, 0.f);
  }
}

// ---------- head layers 1+2 ----------
__global__ __launch_bounds__(256) void k_head_b(const float* __restrict__ h1,
                                                const float* __restrict__ lw1,
                                                const float* __restrict__ lb1,
                                                const float* __restrict__ lw2,
                                                const float* __restrict__ lb2,
                                                float* __restrict__ out) {
  __shared__ float s_in[256];
  __shared__ float part[2][128];
  __shared__ float s_h2[128];
  __shared__ float red[4];
  const int r = blockIdx.x;
  const int t = threadIdx.x;
  s_in[t] = h1[(size_t)r * 256 + t];
  __syncthreads();
  const int l = t & 127, w = t >> 7;
  float acc = 0.f;
  const float* wp = lw1 + (size_t)(w * 128) * 128 + l;
  const float* sp = s_in + w * 128;
#pragma unroll 8
  for (int k = 0; k < 128; ++k) acc = fmaf(sp[k], wp[(size_t)k * 128], acc);
  part[w][l] = acc;
  __syncthreads();
  if (t < 128) s_h2[t] = fmaxf(part[0][t] + part[1][t] + lb1[t], 0.f);
  __syncthreads();
  float p = (t < 128) ? s_h2[t] * lw2[t] : 0.f;
#pragma unroll
  for (int off = 32; off; off >>= 1) p += __shfl_down(p, off);
  if ((t & 63) == 0) red[t >> 6] = p;
  __syncthreads();
  if (t == 0) {
    float z = red[0] + red[1] + red[2] + red[3] + lb2[0];
    out[r] = 1.f / (1.f + expf(-z));
  }
}

extern "C" void kernel_launch(void* const* d_in, const int* in_sizes, int n_in,
                              void* d_out, int out_size, void* d_ws, size_t ws_size,
                              hipStream_t stream) {
  const float* x1 = (const float*)d_in[0];
  const float* x2 = (const float*)d_in[1];
  const int* ei1 = (const int*)d_in[2];
  const int* ei2 = (const int*)d_in[3];
  const int* batch1 = (const int*)d_in[4];
  const int* batch2 = (const int*)d_in[5];
  const float* W0 = (const float*)d_in[6];  const float* b0 = (const float*)d_in[7];
  const float* W1 = (const float*)d_in[8];  const float* b1 = (const float*)d_in[9];
  const float* W2 = (const float*)d_in[10]; const float* b2 = (const float*)d_in[11];
  const float* lw0 = (const float*)d_in[12]; const float* lb0 = (const float*)d_in[13];
  const float* lw1 = (const float*)d_in[14]; const float* lb1 = (const float*)d_in[15];
  const float* lw2 = (const float*)d_in[16]; const float* lb2 = (const float*)d_in[17];
  float* out = (float*)d_out;

  const int N = in_sizes[0] / 128;   // 20000
  const int E = in_sizes[2] / 2;     // 320000
  const int N2 = 2 * N, E2 = 2 * E;
  const int NB = (N2 + 255) / 256;

  char* p = (char*)d_ws;
  unsigned char*  x8   = (unsigned char*)p;  p += (size_t)N2 * 128;      // fp8 input
  unsigned short* aggx = (unsigned short*)p; p += (size_t)N2 * 128 * 2;  // bf16 aggregated x
  unsigned short* h    = (unsigned short*)p; p += (size_t)N2 * HD * 2;   // bf16 activations
  unsigned char*  y    = (unsigned char*)p;  p += (size_t)N2 * HD;       // fp8 pre-activations
  unsigned short* Wt0  = (unsigned short*)p; p += (size_t)128 * HD * 2;
  unsigned short* Wt1  = (unsigned short*)p; p += (size_t)HD * HD * 2;
  unsigned short* Wt2  = (unsigned short*)p; p += (size_t)HD * HD * 2;
  float* dinv   = (float*)p; p += (size_t)N2 * 4;
  float* scores = (float*)p; p += (size_t)GB * 512 * 4;
  float* h1     = (float*)p; p += (size_t)GB * 256 * 4;
  int2* csr    = (int2*)p; p += (size_t)E2 * 8;
  int* deg     = (int*)p; p += (size_t)N2 * 4;
  int* row_ptr = (int*)p; p += (size_t)(N2 + 1) * 4;
  int* cursor  = (int*)p; p += (size_t)N2 * 4;
  int* partial = (int*)p; p += 256 * 4;

  // prep: weights pack + x->fp8 + zero scores/deg, one kernel
  int n4 = N * 128 / 4;
  int prep_total = 163840 + 2 * n4 + GB * 512 + N2;
  k_prep<<<(prep_total + 255) / 256, 256, 0, stream>>>(
      W0, W1, W2, Wt0, Wt1, Wt2,
      (const float4*)x1, (const float4*)x2, (unsigned*)x8, n4, scores, deg, N2);

  // merged CSR
  k_deg2<<<(2 * E + 255) / 256, 256, 0, stream>>>(ei1 + E, ei2 + E, deg, E, N);
  k_scan_a<<<NB, 256, 0, stream>>>(deg, partial, N2);
  k_scan_b<<<1, 256, 0, stream>>>(partial, NB, row_ptr, N2, E2);
  k_scan_c<<<NB, 256, 0, stream>>>(deg, partial, row_ptr, dinv, cursor, N2);
  k_build2<<<(2 * E + 255) / 256, 256, 0, stream>>>(ei1, ei2, dinv, row_ptr,
                                                    cursor, csr, E, N);

  dim3 ggrid(N2 / 64, 2);
  // layer 0: aggregate fp8 x (128-dim), then bf16 GEMM with bias+relu -> h (bf16)
  k_gathf8<2, false><<<(N2 + 3) / 4, 256, 0, stream>>>(x8, row_ptr, csr, dinv,
                                                       nullptr, aggx, N2);
  k_gemm_bf<true, false><<<ggrid, 256, 0, stream>>>(aggx, Wt0, b0, h, 128);
  // layer 1
  k_gemm_bf<false, true><<<ggrid, 256, 0, stream>>>(h, Wt1, nullptr, y, HD);
  k_gathf8<4, true><<<(N2 + 3) / 4, 256, 0, stream>>>(y, row_ptr, csr, dinv,
                                                      b1, h, N2);
  // layer 2
  k_gemm_bf<false, true><<<ggrid, 256, 0, stream>>>(h, Wt2, nullptr, y, HD);
  k_gathf8<4, true><<<(N2 + 3) / 4, 256, 0, stream>>>(y, row_ptr, csr, dinv,
                                                      b2, h, N2);

  int waves = N2 / 32;
  k_pool4<<<(waves + 3) / 4, 256, 0, stream>>>(h, batch1, batch2, scores, N2, N);

  dim3 hgrid(GB, 4);
  k_head_a<<<hgrid, 256, 0, stream>>>(scores, lw0, lb0, h1);
  k_head_b<<<GB, 256, 0, stream>>>(h1, lw1, lb1, lw2, lb2, out);
}